// Round 4
// baseline (430.779 us; speedup 1.0000x reference)
//
#include <hip/hip_runtime.h>
#include <hip/hip_bf16.h>

#define FLOAT_EPS 1.1920928955078125e-07f

typedef float f32x4 __attribute__((ext_vector_type(4)));
typedef short s16x8 __attribute__((ext_vector_type(8)));

#define B_ 16
#define P_ 8192
#define I_ 256
#define O_ 128
#define L_ 256
#define IO_ (I_*O_)   // 32768

__device__ __forceinline__ float clip01(float v) {
    return fminf(fmaxf(v, 0.0f), 1.0f);
}
__device__ __forceinline__ f32x4 clip01v(f32x4 v) {
    f32x4 r;
    r[0] = clip01(v[0]); r[1] = clip01(v[1]);
    r[2] = clip01(v[2]); r[3] = clip01(v[3]);
    return r;
}

// ---------------- K1: partial logits, l split 2-way; lat read via scalar loads ------
// grid (128, 2, 2) = (n-block, ks, l-half), block 256.
__global__ __launch_bounds__(256) void rl_k1_logits(
        const float* __restrict__ lat,
        const float* __restrict__ c1, const float* __restrict__ c2,
        float* __restrict__ lgP) {
    const int n  = blockIdx.x * 256 + threadIdx.x;
    const int ks = blockIdx.y;
    const int lh = blockIdx.z;
    const float* __restrict__ C  = (ks ? c2 : c1) + (size_t)lh * 128 * IO_;
    const int lbase = lh * 128;

    float acc[16];
#pragma unroll
    for (int b = 0; b < 16; ++b) acc[b] = 0.0f;

#pragma unroll 4
    for (int l = 0; l < 128; ++l) {
        float cv = C[(size_t)l * IO_ + n];
#pragma unroll
        for (int b = 0; b < 16; ++b)
            acc[b] += lat[b * L_ + lbase + l] * cv;   // uniform -> s_load
    }
    float* o = lgP + ((size_t)(lh * 32 + ks * 16)) * IO_ + n;
#pragma unroll
    for (int b = 0; b < 16; ++b) o[(size_t)b * IO_] = acc[b];
}

// ---------------- K2: double softmax over i, write M_T[b][n][i] bf16 ----------------
// grid (8, 2, 16) = (o-tile16, ks, b), block 256 = 16 i-groups x 16 o-lanes.
__global__ __launch_bounds__(256) void rl_k2_mask(
        const float* __restrict__ lgP, const float* __restrict__ u,
        const float* __restrict__ temp_p, __hip_bfloat16* __restrict__ MT) {
    const int oo = threadIdx.x & 15;
    const int g  = threadIdx.x >> 4;     // 16 groups, 16 i's each
    const int o0 = blockIdx.x * 16;
    const int ks = blockIdx.y;
    const int b  = blockIdx.z;

    __shared__ float slab[I_][16];
    __shared__ float red[16][16];

    const float* __restrict__ z0 = lgP + (size_t)(ks * 16 + b) * IO_ + o0 + oo;
    const float* __restrict__ z1 = z0 + (size_t)32 * IO_;
    const float* __restrict__ up = u + ((size_t)b * 2 + ks) * IO_ + o0 + oo;

    float T = temp_p[0];
    T = fminf(fmaxf(T, FLOAT_EPS), 2.0f);
    T = fmaxf(T, 0.001f);
    const float rT = 1.0f / T;

    const int i0 = g * 16, i1 = i0 + 16;

    for (int i = i0; i < i1; ++i)
        slab[i][oo] = z0[(size_t)i * O_] + z1[(size_t)i * O_];
    __syncthreads();

    float m = -INFINITY;
    for (int i = i0; i < i1; ++i) m = fmaxf(m, slab[i][oo]);
    red[g][oo] = m; __syncthreads();
    m = -INFINITY;
#pragma unroll
    for (int j = 0; j < 16; ++j) m = fmaxf(m, red[j][oo]);
    __syncthreads();

    float S = 0.0f;
    for (int i = i0; i < i1; ++i) S += expf(slab[i][oo] - m);
    red[g][oo] = S; __syncthreads();
    S = 0.0f;
#pragma unroll
    for (int j = 0; j < 16; ++j) S += red[j][oo];
    __syncthreads();
    const float invS = 1.0f / S;

    float m2 = -INFINITY;
    for (int i = i0; i < i1; ++i) {
        float p  = expf(slab[i][oo] - m) * invS;
        float uu = fmaxf(up[(size_t)i * O_], FLOAT_EPS);
        float gg = -logf(-logf(uu));
        float s  = (logf(p + FLOAT_EPS) + gg) * rT;
        slab[i][oo] = s;
        m2 = fmaxf(m2, s);
    }
    red[g][oo] = m2; __syncthreads();
    m2 = -INFINITY;
#pragma unroll
    for (int j = 0; j < 16; ++j) m2 = fmaxf(m2, red[j][oo]);
    __syncthreads();

    float S2 = 0.0f;
    for (int i = i0; i < i1; ++i) S2 += expf(slab[i][oo] - m2);
    red[g][oo] = S2; __syncthreads();
    S2 = 0.0f;
#pragma unroll
    for (int j = 0; j < 16; ++j) S2 += red[j][oo];
    const float invS2 = 1.0f / S2;

    __hip_bfloat16* __restrict__ row = MT + ((size_t)(b * 256 + ks * 128 + o0 + oo)) * I_;
    for (int i = i0; i < i1; i += 2) {
        float v0 = expf(slab[i][oo]     - m2) * invS2;
        float v1 = expf(slab[i + 1][oo] - m2) * invS2;
        __hip_bfloat162 pk = __float22bfloat162_rn(make_float2(v0, v1));
        *(__hip_bfloat162*)(row + i) = pk;
    }
}

// ---------------- K3: streaming GEMM, swapped-operand MFMA for coalesced stores -----
// grid (16, 16) = (512-row slab, b), block 512 = 8 waves, 64 rows/wave in 4 chunks of 16.
// mfma(A=mask, B=x) -> D[n][p]: lane col = output row p, regs = 4 consecutive n.
// Epilogue: 32 dwordx4 stores per chunk (fully coalesced 64B runs), vmcnt never
// forced to drain the store queue (32 stores < vmcnt max 63).
__global__ __launch_bounds__(512, 2) void rl_k3_gemm(
        const float* __restrict__ X, const __hip_bfloat16* __restrict__ MT,
        float* __restrict__ OUT) {
    const int tid  = threadIdx.x;
    const int lane = tid & 63, wid = tid >> 6;
    const int b    = blockIdx.y;

    __shared__ short Blds[256 * 256];   // 128 KB, XOR-swizzled byte ^= (n&7)<<4

    const float* __restrict__ Xb           = X   + (size_t)b * P_ * I_;
    const __hip_bfloat16* __restrict__ MTb = MT  + (size_t)b * 65536;
    float* __restrict__ Ob                 = OUT + (size_t)b * P_ * 512;

    const int l15 = lane & 15, lhi = lane >> 4;
    const int rowbase = blockIdx.x * 512 + wid * 64 + l15;

    // 1. issue x chunk-0 prefetch FIRST (latency hides under B staging)
    float4 raw[16];
    {
        const float* s0 = Xb + (size_t)rowbase * I_ + lhi * 8;
#pragma unroll
        for (int kk = 0; kk < 8; ++kk) {
            raw[2 * kk]     = *(const float4*)(s0 + kk * 32);
            raw[2 * kk + 1] = *(const float4*)(s0 + kk * 32 + 4);
        }
    }

    // 2. load B cooperatively (swizzled)
#pragma unroll
    for (int it = 0; it < 16; ++it) {
        int idx = it * 512 + tid;          // chunks of 8 bf16
        int n = idx >> 5, c = idx & 31;
        s16x8 v = *(const s16x8*)(MTb + n * 256 + c * 8);
        *(s16x8*)((char*)Blds + n * 512 + ((c * 16) ^ ((n & 7) << 4))) = v;
    }
    __syncthreads();

    for (int c = 0; c < 4; ++c) {
        // convert raw -> af (x fragments, used as MFMA B-operand)
        s16x8 af[8];
#pragma unroll
        for (int kk = 0; kk < 8; ++kk) {
            float4 f0 = raw[2 * kk], f1 = raw[2 * kk + 1];
            union { s16x8 v; __hip_bfloat162 h[4]; } cv;
            cv.h[0] = __float22bfloat162_rn(make_float2(f0.x, f0.y));
            cv.h[1] = __float22bfloat162_rn(make_float2(f0.z, f0.w));
            cv.h[2] = __float22bfloat162_rn(make_float2(f1.x, f1.y));
            cv.h[3] = __float22bfloat162_rn(make_float2(f1.z, f1.w));
            af[kk] = cv.v;
        }
        // prefetch chunk c+1 (stays in flight under MFMA + stores)
        if (c < 3) {
            const float* s1 = Xb + (size_t)(rowbase + (c + 1) * 16) * I_ + lhi * 8;
#pragma unroll
            for (int kk = 0; kk < 8; ++kk) {
                raw[2 * kk]     = *(const float4*)(s1 + kk * 32);
                raw[2 * kk + 1] = *(const float4*)(s1 + kk * 32 + 4);
            }
        }

        f32x4 acc[16];
#pragma unroll
        for (int j = 0; j < 16; ++j) acc[j] = (f32x4){0.f, 0.f, 0.f, 0.f};

        __builtin_amdgcn_s_setprio(1);
#pragma unroll
        for (int kk = 0; kk < 8; ++kk) {
            const int kb = kk * 64 + lhi * 16;   // byte offset in mask row
#pragma unroll
            for (int fn = 0; fn < 16; ++fn) {
                int n = fn * 16 + l15;
                s16x8 bf = *(const s16x8*)((const char*)Blds + n * 512 + (kb ^ ((n & 7) << 4)));
                // A = mask (rows n), B = x (cols p) -> D[n][p]
                acc[fn] = __builtin_amdgcn_mfma_f32_16x16x32_bf16(bf, af[kk], acc[fn], 0, 0, 0);
            }
        }
        __builtin_amdgcn_s_setprio(0);

        // epilogue: lane owns output row (prow + l15); regs = 4 consecutive cols
        const int prow = blockIdx.x * 512 + wid * 64 + c * 16 + l15;
        float* __restrict__ oprow = Ob + (size_t)prow * 512 + lhi * 4;
#pragma unroll
        for (int fn = 0; fn < 8; ++fn) {
            f32x4 va = acc[fn], vb = acc[fn + 8];
            f32x4 s  = va + vb;
            float* op = oprow + fn * 16;
            *(f32x4*)(op)       = clip01v(s);
            *(f32x4*)(op + 128) = clip01v(s - 1.0f);
            *(f32x4*)(op + 256) = clip01v(va - vb);
            *(f32x4*)(op + 384) = clip01v(vb - va);
        }
    }
}

extern "C" void kernel_launch(void* const* d_in, const int* in_sizes, int n_in,
                              void* d_out, int out_size, void* d_ws, size_t ws_size,
                              hipStream_t stream) {
    const float* x    = (const float*)d_in[0];
    const float* lat  = (const float*)d_in[1];
    const float* c1   = (const float*)d_in[2];
    const float* c2   = (const float*)d_in[3];
    const float* temp = (const float*)d_in[4];
    const float* u    = (const float*)d_in[5];
    float* out = (float*)d_out;

    char* ws = (char*)d_ws;
    float*          lgP = (float*)ws;                          // 8 MB
    __hip_bfloat16* MT  = (__hip_bfloat16*)(ws + (8 << 20));   // 2 MB

    rl_k1_logits<<<dim3(128, 2, 2), 256, 0, stream>>>(lat, c1, c2, lgP);
    rl_k2_mask  <<<dim3(8, 2, 16), 256, 0, stream>>>(lgP, u, temp, MT);
    rl_k3_gemm  <<<dim3(16, 16), 512, 0, stream>>>(x, MT, out);
}

// Round 5
// 138.202 us; speedup vs baseline: 3.1170x; 3.1170x over previous
//
#include <hip/hip_runtime.h>
#include <hip/hip_bf16.h>

#define FLOAT_EPS 1.1920928955078125e-07f

typedef float f32x4 __attribute__((ext_vector_type(4)));
typedef short s16x8 __attribute__((ext_vector_type(8)));

#define B_ 16
#define P_ 8192
#define I_ 256
#define O_ 128
#define L_ 256
#define IO_ (I_*O_)   // 32768

__device__ __forceinline__ float clip01(float v) {
    return fminf(fmaxf(v, 0.0f), 1.0f);
}
__device__ __forceinline__ f32x4 clip01v(f32x4 v) {
    f32x4 r;
    r[0] = clip01(v[0]); r[1] = clip01(v[1]);
    r[2] = clip01(v[2]); r[3] = clip01(v[3]);
    return r;
}

// ---------------- K1: partial logits, l split 2-way; lat read via scalar loads ------
// grid (128, 2, 2) = (n-block, ks, l-half), block 256.
__global__ __launch_bounds__(256) void rl_k1_logits(
        const float* __restrict__ lat,
        const float* __restrict__ c1, const float* __restrict__ c2,
        float* __restrict__ lgP) {
    const int n  = blockIdx.x * 256 + threadIdx.x;
    const int ks = blockIdx.y;
    const int lh = blockIdx.z;
    const float* __restrict__ C  = (ks ? c2 : c1) + (size_t)lh * 128 * IO_;
    const int lbase = lh * 128;

    float acc[16];
#pragma unroll
    for (int b = 0; b < 16; ++b) acc[b] = 0.0f;

#pragma unroll 4
    for (int l = 0; l < 128; ++l) {
        float cv = C[(size_t)l * IO_ + n];
#pragma unroll
        for (int b = 0; b < 16; ++b)
            acc[b] += lat[b * L_ + lbase + l] * cv;   // uniform -> s_load
    }
    float* o = lgP + ((size_t)(lh * 32 + ks * 16)) * IO_ + n;
#pragma unroll
    for (int b = 0; b < 16; ++b) o[(size_t)b * IO_] = acc[b];
}

// ---------------- K2: double softmax over i, write M_T[b][n][i] bf16 ----------------
// grid (8, 2, 16) = (o-tile16, ks, b), block 256 = 16 i-groups x 16 o-lanes.
__global__ __launch_bounds__(256) void rl_k2_mask(
        const float* __restrict__ lgP, const float* __restrict__ u,
        const float* __restrict__ temp_p, __hip_bfloat16* __restrict__ MT) {
    const int oo = threadIdx.x & 15;
    const int g  = threadIdx.x >> 4;     // 16 groups, 16 i's each
    const int o0 = blockIdx.x * 16;
    const int ks = blockIdx.y;
    const int b  = blockIdx.z;

    __shared__ float slab[I_][16];
    __shared__ float red[16][16];

    const float* __restrict__ z0 = lgP + (size_t)(ks * 16 + b) * IO_ + o0 + oo;
    const float* __restrict__ z1 = z0 + (size_t)32 * IO_;
    const float* __restrict__ up = u + ((size_t)b * 2 + ks) * IO_ + o0 + oo;

    float T = temp_p[0];
    T = fminf(fmaxf(T, FLOAT_EPS), 2.0f);
    T = fmaxf(T, 0.001f);
    const float rT = 1.0f / T;

    const int i0 = g * 16, i1 = i0 + 16;

    for (int i = i0; i < i1; ++i)
        slab[i][oo] = z0[(size_t)i * O_] + z1[(size_t)i * O_];
    __syncthreads();

    float m = -INFINITY;
    for (int i = i0; i < i1; ++i) m = fmaxf(m, slab[i][oo]);
    red[g][oo] = m; __syncthreads();
    m = -INFINITY;
#pragma unroll
    for (int j = 0; j < 16; ++j) m = fmaxf(m, red[j][oo]);
    __syncthreads();

    float S = 0.0f;
    for (int i = i0; i < i1; ++i) S += expf(slab[i][oo] - m);
    red[g][oo] = S; __syncthreads();
    S = 0.0f;
#pragma unroll
    for (int j = 0; j < 16; ++j) S += red[j][oo];
    __syncthreads();
    const float invS = 1.0f / S;

    float m2 = -INFINITY;
    for (int i = i0; i < i1; ++i) {
        float p  = expf(slab[i][oo] - m) * invS;
        float uu = fmaxf(up[(size_t)i * O_], FLOAT_EPS);
        float gg = -logf(-logf(uu));
        float s  = (logf(p + FLOAT_EPS) + gg) * rT;
        slab[i][oo] = s;
        m2 = fmaxf(m2, s);
    }
    red[g][oo] = m2; __syncthreads();
    m2 = -INFINITY;
#pragma unroll
    for (int j = 0; j < 16; ++j) m2 = fmaxf(m2, red[j][oo]);
    __syncthreads();

    float S2 = 0.0f;
    for (int i = i0; i < i1; ++i) S2 += expf(slab[i][oo] - m2);
    red[g][oo] = S2; __syncthreads();
    S2 = 0.0f;
#pragma unroll
    for (int j = 0; j < 16; ++j) S2 += red[j][oo];
    const float invS2 = 1.0f / S2;

    __hip_bfloat16* __restrict__ row = MT + ((size_t)(b * 256 + ks * 128 + o0 + oo)) * I_;
    for (int i = i0; i < i1; i += 2) {
        float v0 = expf(slab[i][oo]     - m2) * invS2;
        float v1 = expf(slab[i + 1][oo] - m2) * invS2;
        __hip_bfloat162 pk = __float22bfloat162_rn(make_float2(v0, v1));
        *(__hip_bfloat162*)(row + i) = pk;
    }
}

// ---------------- K3: streaming GEMM, swapped-operand MFMA, fn-outer (low VGPR) -----
// grid (16, 16) = (512-row slab, b), block 512 = 8 waves, 64 rows/wave in 4 chunks of 16.
// mfma(A=mask, B=x) -> D[n][p]: lane col (l15) = output row p, regs = 4 consecutive n.
// fn outer loop: only acc_a/acc_b (8 VGPR) live per pair -> peak ~110 VGPR, no spill.
__global__ __launch_bounds__(512, 2) void rl_k3_gemm(
        const float* __restrict__ X, const __hip_bfloat16* __restrict__ MT,
        float* __restrict__ OUT) {
    const int tid  = threadIdx.x;
    const int lane = tid & 63, wid = tid >> 6;
    const int b    = blockIdx.y;

    __shared__ short Blds[256 * 256];   // 128 KB, XOR-swizzled byte ^= (n&7)<<4

    const float* __restrict__ Xb           = X   + (size_t)b * P_ * I_;
    const __hip_bfloat16* __restrict__ MTb = MT  + (size_t)b * 65536;
    float* __restrict__ Ob                 = OUT + (size_t)b * P_ * 512;

    const int l15 = lane & 15, lhi = lane >> 4;
    const int rowbase = blockIdx.x * 512 + wid * 64 + l15;

    // stage B cooperatively (swizzled)
#pragma unroll
    for (int it = 0; it < 16; ++it) {
        int idx = it * 512 + tid;          // chunks of 8 bf16
        int n = idx >> 5, c = idx & 31;
        s16x8 v = *(const s16x8*)(MTb + n * 256 + c * 8);
        *(s16x8*)((char*)Blds + n * 512 + ((c * 16) ^ ((n & 7) << 4))) = v;
    }

    // prefetch x chunk 0 (latency hides under B staging + barrier)
    float4 raw[16];
    {
        const float* s0 = Xb + (size_t)rowbase * I_ + lhi * 8;
#pragma unroll
        for (int kk = 0; kk < 8; ++kk) {
            raw[2 * kk]     = *(const float4*)(s0 + kk * 32);
            raw[2 * kk + 1] = *(const float4*)(s0 + kk * 32 + 4);
        }
    }
    __syncthreads();

    for (int c = 0; c < 4; ++c) {
        // convert raw -> af (x fragments, MFMA B-operand)
        s16x8 af[8];
#pragma unroll
        for (int kk = 0; kk < 8; ++kk) {
            float4 f0 = raw[2 * kk], f1 = raw[2 * kk + 1];
            union { s16x8 v; __hip_bfloat162 h[4]; } cv;
            cv.h[0] = __float22bfloat162_rn(make_float2(f0.x, f0.y));
            cv.h[1] = __float22bfloat162_rn(make_float2(f0.z, f0.w));
            cv.h[2] = __float22bfloat162_rn(make_float2(f1.x, f1.y));
            cv.h[3] = __float22bfloat162_rn(make_float2(f1.z, f1.w));
            af[kk] = cv.v;
        }
        // prefetch chunk c+1; sched_barrier pins it here (can't sink below compute)
        if (c < 3) {
            const float* s1 = Xb + (size_t)(rowbase + (c + 1) * 16) * I_ + lhi * 8;
#pragma unroll
            for (int kk = 0; kk < 8; ++kk) {
                raw[2 * kk]     = *(const float4*)(s1 + kk * 32);
                raw[2 * kk + 1] = *(const float4*)(s1 + kk * 32 + 4);
            }
        }
        __builtin_amdgcn_sched_barrier(0);

        const int prow = blockIdx.x * 512 + wid * 64 + c * 16 + l15;
        float* __restrict__ oprow = Ob + (size_t)prow * 512 + lhi * 4;

#pragma unroll
        for (int fn = 0; fn < 8; ++fn) {
            f32x4 acc_a = (f32x4){0.f, 0.f, 0.f, 0.f};
            f32x4 acc_b = (f32x4){0.f, 0.f, 0.f, 0.f};
            const int na = fn * 16 + l15;         // a-half row
            const int nb = na + 128;              // b-half row
            const char* rowA = (const char*)Blds + na * 512;
            const char* rowB = (const char*)Blds + nb * 512;
            const int swz = (na & 7) << 4;        // same for na and nb
#pragma unroll
            for (int kk = 0; kk < 8; ++kk) {
                const int kb = (kk * 64 + lhi * 16) ^ swz;
                s16x8 bfa = *(const s16x8*)(rowA + kb);
                s16x8 bfb = *(const s16x8*)(rowB + kb);
                acc_a = __builtin_amdgcn_mfma_f32_16x16x32_bf16(bfa, af[kk], acc_a, 0, 0, 0);
                acc_b = __builtin_amdgcn_mfma_f32_16x16x32_bf16(bfb, af[kk], acc_b, 0, 0, 0);
            }
            // lane owns output row prow; regs = 4 consecutive n (cols)
            f32x4 s = acc_a + acc_b;
            float* op = oprow + fn * 16;
            __builtin_nontemporal_store(clip01v(s),             (f32x4*)(op));
            __builtin_nontemporal_store(clip01v(s - 1.0f),      (f32x4*)(op + 128));
            __builtin_nontemporal_store(clip01v(acc_a - acc_b), (f32x4*)(op + 256));
            __builtin_nontemporal_store(clip01v(acc_b - acc_a), (f32x4*)(op + 384));
        }
    }
}

extern "C" void kernel_launch(void* const* d_in, const int* in_sizes, int n_in,
                              void* d_out, int out_size, void* d_ws, size_t ws_size,
                              hipStream_t stream) {
    const float* x    = (const float*)d_in[0];
    const float* lat  = (const float*)d_in[1];
    const float* c1   = (const float*)d_in[2];
    const float* c2   = (const float*)d_in[3];
    const float* temp = (const float*)d_in[4];
    const float* u    = (const float*)d_in[5];
    float* out = (float*)d_out;

    char* ws = (char*)d_ws;
    float*          lgP = (float*)ws;                          // 8 MB
    __hip_bfloat16* MT  = (__hip_bfloat16*)(ws + (8 << 20));   // 2 MB

    rl_k1_logits<<<dim3(128, 2, 2), 256, 0, stream>>>(lat, c1, c2, lgP);
    rl_k2_mask  <<<dim3(8, 2, 16), 256, 0, stream>>>(lgP, u, temp, MT);
    rl_k3_gemm  <<<dim3(16, 16), 512, 0, stream>>>(x, MT, out);
}